// Round 11
// baseline (275.453 us; speedup 1.0000x reference)
//
#include <hip/hip_runtime.h>
#include <hip/hip_bf16.h>

#define NPIX 3136
#define BB 4
#define LOG2E 1.4426950408889634f

typedef unsigned short u16;
typedef __bf16 bf16x8 __attribute__((ext_vector_type(8)));
typedef float f32x4 __attribute__((ext_vector_type(4)));

__device__ __forceinline__ float b2f(u16 u) {
  union { unsigned u; float f; } c; c.u = ((unsigned)u) << 16; return c.f;
}
__device__ __forceinline__ u16 f2b(float f) {
  __hip_bfloat16 h = __float2bfloat16(f);
  return *reinterpret_cast<u16*>(&h);
}
__device__ __forceinline__ unsigned pk2(float a, float b) {
  return (unsigned)f2b(a) | ((unsigned)f2b(b) << 16);
}
__device__ __forceinline__ f32x4 mfma(bf16x8 a, bf16x8 b, f32x4 c) {
  return __builtin_amdgcn_mfma_f32_16x16x32_bf16(a, b, c, 0, 0, 0);
}

// ---------------------------------------------------------------------------
// 2-tile MFMA wave-GEMM (unchanged, used by ff1/ff3).
// ---------------------------------------------------------------------------
template<int NSTEP, int NOT>
__device__ __forceinline__ void mf_gemm2(const u16* __restrict__ A0,
                                         const u16* __restrict__ A1,
                                         const u16* __restrict__ Brow, int sB,
                                         int lq, f32x4* acc) {
#pragma unroll
  for (int s = 0; s < NSTEP; ++s) {
    bf16x8 bf[NOT];
#pragma unroll
    for (int ot = 0; ot < NOT; ++ot)
      bf[ot] = *(const bf16x8*)(Brow + (size_t)ot * 16 * sB + s * 32 + lq * 8);
    bf16x8 a0 = *(const bf16x8*)(A0 + s * 32 + lq * 8);
    bf16x8 a1 = *(const bf16x8*)(A1 + s * 32 + lq * 8);
#pragma unroll
    for (int ot = 0; ot < NOT; ++ot) {
      acc[ot] = mfma(a0, bf[ot], acc[ot]);
      acc[NOT + ot] = mfma(a1, bf[ot], acc[NOT + ot]);
    }
  }
}

// ---------------------------------------------------------------------------
// prep_w: weights -> bf16. theta weights pre-scaled by log2(e).
// f2w repacked tap-major [t][co][ci].
// ---------------------------------------------------------------------------
__global__ __launch_bounds__(256) void prep_w(
    const float* __restrict__ gw, const float* __restrict__ tw,
    const float* __restrict__ pw, const float* __restrict__ Ww,
    const float* __restrict__ f1w, const float* __restrict__ f2w,
    const float* __restrict__ f3w,
    u16* __restrict__ gwb, u16* __restrict__ twb, u16* __restrict__ pwb,
    u16* __restrict__ Wwb, u16* __restrict__ f1b, u16* __restrict__ f3b,
    u16* __restrict__ f2p) {
  for (int i = blockIdx.x * 256 + threadIdx.x; i < 200704; i += gridDim.x * 256) {
    int j = i;
    if (j < 32768) { gwb[j] = f2b(gw[j]); continue; } j -= 32768;
    if (j < 32768) { twb[j] = f2b(tw[j] * LOG2E); continue; } j -= 32768;
    if (j < 32768) { pwb[j] = f2b(pw[j]); continue; } j -= 32768;
    if (j < 32768) { Wwb[j] = f2b(Ww[j]); continue; } j -= 32768;
    if (j < 16384) { f1b[j] = f2b(f1w[j]); continue; } j -= 16384;
    if (j < 16384) { f3b[j] = f2b(f3w[j]); continue; } j -= 16384;
    int t = j >> 12, rem = j & 4095, co = rem >> 6, ci = rem & 63;
    f2p[j] = f2b(f2w[(co * 64 + ci) * 9 + t]);
  }
}

// ---------------------------------------------------------------------------
// proj (absorbs prep_x): block stages its 64n x 256c x-tile into LDS
// (fp32 read, bf16 n-major transpose, stride 264 u16 -> 2-way-free banks),
// then 4 waves loop the 6 output sections (g lo/hi, theta lo/hi, phi lo/hi).
// Grid (49, BB). No n-tail (49*64 = 3136).
// ---------------------------------------------------------------------------
__global__ __launch_bounds__(256) void proj_kernel(
    const float* __restrict__ x,
    const u16* __restrict__ gwb, const u16* __restrict__ twb, const u16* __restrict__ pwb,
    const float* __restrict__ gb, const float* __restrict__ tb, const float* __restrict__ pb,
    u16* __restrict__ gx, u16* __restrict__ Tq, u16* __restrict__ Pk) {
  __shared__ __align__(16) u16 sA[64 * 264];
  const int b = blockIdx.y, nb = blockIdx.x * 64;
  const int tid = threadIdx.x;
  const int cb16 = tid >> 4, jj = tid & 15;
#pragma unroll 4
  for (int cb = 0; cb < 16; ++cb) {
    int c = cb * 16 + cb16;
    float4 v = *(const float4*)(x + ((size_t)(b * 256 + c)) * NPIX + nb + jj * 4);
    int n0 = jj * 4;
    sA[(n0 + 0) * 264 + c] = f2b(v.x);
    sA[(n0 + 1) * 264 + c] = f2b(v.y);
    sA[(n0 + 2) * 264 + c] = f2b(v.z);
    sA[(n0 + 3) * 264 + c] = f2b(v.w);
  }
  __syncthreads();
  const int wv = tid >> 6, lane = tid & 63;
  const int lr = lane & 15, lq = lane >> 4;
  const int nrow = nb + wv * 16;
#pragma unroll 1
  for (int sec = 0; sec < 6; ++sec) {
    const int st = sec >> 1, rbase = (sec & 1) * 64;
    const u16* wsel = st == 0 ? gwb : (st == 1 ? twb : pwb);
    const float* bsel = st == 0 ? gb : (st == 1 ? tb : pb);
    f32x4 acc[4] = {};
#pragma unroll
    for (int s = 0; s < 8; ++s) {
      bf16x8 af = *(const bf16x8*)(sA + (wv * 16 + lr) * 264 + s * 32 + lq * 8);
#pragma unroll
      for (int ot = 0; ot < 4; ++ot) {
        bf16x8 bf = *(const bf16x8*)(wsel + (size_t)(rbase + ot * 16 + lr) * 256 + s * 32 + lq * 8);
        acc[ot] = mfma(af, bf, acc[ot]);
      }
    }
    const int qn = nrow + lq * 4;
#pragma unroll
    for (int ot = 0; ot < 4; ++ot) {
      const int o = rbase + ot * 16 + lr;
      float bias = bsel[o];
      if (st == 1) bias *= LOG2E;
      if (st == 0) {
        uint2 s2;
        s2.x = pk2(acc[ot][0] + bias, acc[ot][1] + bias);
        s2.y = pk2(acc[ot][2] + bias, acc[ot][3] + bias);
        *(uint2*)(gx + ((size_t)b * 128 + o) * NPIX + qn) = s2;
      } else {
        const int g = o >> 5, dl = o & 31;
        u16* dst = st == 1 ? Tq : Pk;
        size_t base = (size_t)(b * 4 + g) * NPIX;
#pragma unroll
        for (int r = 0; r < 4; ++r)
          dst[(base + qn + r) * 32 + dl] = f2b(acc[ot][r] + bias);
      }
    }
  }
}

// ---------------------------------------------------------------------------
// attn: UNCHANGED from R10 (74.4 us, no spills).
// ---------------------------------------------------------------------------
__global__ __launch_bounds__(256) void attn_kernel(
    const u16* __restrict__ Tq, const u16* __restrict__ Pk,
    const u16* __restrict__ gx, u16* __restrict__ OPb, float* __restrict__ LP) {
  __shared__ __align__(16) u16 Plds[4][32][40];
  const int bid = blockIdx.x;
  const int ks = bid / 400, rem = bid % 400;
  const int bg = rem / 25, qblk = rem % 25;
  const int b = bg >> 2, g = bg & 3;
  const int wave = threadIdx.x >> 6, lane = threadIdx.x & 63;
  const int lr = lane & 15, lq = lane >> 4;
  const int qbase = qblk * 128 + wave * 32;
  const int kc0 = ks * 448;
  const u16* Qp = Tq + (size_t)bg * NPIX * 32;
  const u16* Kp = Pk + (size_t)bg * NPIX * 32;
  const u16* Vp = gx + ((size_t)b * 128 + g * 32) * NPIX;

  bf16x8 qf[2];
#pragma unroll
  for (int qi = 0; qi < 2; ++qi) {
    int row = qbase + qi * 16 + lr;
    row = row < NPIX ? row : NPIX - 1;
    qf[qi] = *(const bf16x8*)(Qp + (size_t)row * 32 + lq * 8);
  }
  const f32x4 z4 = {0.f, 0.f, 0.f, 0.f};
  f32x4 O[2][2], Lf[2];
#pragma unroll
  for (int qi = 0; qi < 2; ++qi) { O[qi][0] = z4; O[qi][1] = z4; Lf[qi] = z4; }
  bf16x8 onef;
#pragma unroll
  for (int j = 0; j < 8; ++j) onef[j] = (__bf16)1.0f;

#pragma unroll 1
  for (int kc = kc0; kc < kc0 + 448; kc += 32) {
    bf16x8 kf0 = *(const bf16x8*)(Kp + (size_t)(kc + lr) * 32 + lq * 8);
    bf16x8 kf1 = *(const bf16x8*)(Kp + (size_t)(kc + 16 + lr) * 32 + lq * 8);
    f32x4 S[2][2];
    S[0][0] = mfma(qf[0], kf0, z4);
    S[0][1] = mfma(qf[0], kf1, z4);
    S[1][0] = mfma(qf[1], kf0, z4);
    S[1][1] = mfma(qf[1], kf1, z4);
#pragma unroll
    for (int qi = 0; qi < 2; ++qi)
#pragma unroll
      for (int kt = 0; kt < 2; ++kt)
#pragma unroll
        for (int r = 0; r < 4; ++r) {
          unsigned u = __builtin_bit_cast(unsigned, __builtin_exp2f(S[qi][kt][r]));
          Plds[wave][qi * 16 + lq * 4 + r][kt * 16 + lr] = (u16)(u >> 16);
        }
    bf16x8 pf0 = *(const bf16x8*)(&Plds[wave][lr][lq * 8]);
    bf16x8 pf1 = *(const bf16x8*)(&Plds[wave][16 + lr][lq * 8]);
    bf16x8 vf0 = *(const bf16x8*)(Vp + (size_t)lr * NPIX + kc + lq * 8);
    bf16x8 vf1 = *(const bf16x8*)(Vp + (size_t)(16 + lr) * NPIX + kc + lq * 8);
    O[0][0] = mfma(pf0, vf0, O[0][0]);
    O[0][1] = mfma(pf0, vf1, O[0][1]);
    O[1][0] = mfma(pf1, vf0, O[1][0]);
    O[1][1] = mfma(pf1, vf1, O[1][1]);
    Lf[0] = mfma(pf0, onef, Lf[0]);
    Lf[1] = mfma(pf1, onef, Lf[1]);
  }
  const size_t sbase = (size_t)(ks * 16 + bg) * NPIX;
#pragma unroll
  for (int qi = 0; qi < 2; ++qi) {
#pragma unroll
    for (int r = 0; r < 4; ++r) {
      int qrow = qbase + qi * 16 + lq * 4 + r;
      if (qrow < NPIX) {
        size_t ob = (sbase + qrow) * 32;
        OPb[ob + lr] = f2b(O[qi][0][r]);
        OPb[ob + 16 + lr] = f2b(O[qi][1][r]);
        if (lr == 0) LP[sbase + qrow] = Lf[qi][r];
      }
    }
  }
}

// ---------------------------------------------------------------------------
// wz (absorbs combine via MFMA linearity): z = relu(bn(W@(O/l) + Wb) + x).
// Per k-group g (32 ch), keep separate accumulators; accumulate raw bf16
// partials over ks=0..6 directly with MFMA (no unpack/repack); apply the
// per-(g,row) 1/l scale in the epilogue (softmax norm differs per group so
// it cannot commute past the channel sum). Grid (49, 4oc, BB), 1-tile 16nx64o.
// ---------------------------------------------------------------------------
__global__ __launch_bounds__(256) void wz_kernel(
    const u16* __restrict__ OPb, const float* __restrict__ LP,
    const u16* __restrict__ Wwb, const float* __restrict__ Wb,
    const float* __restrict__ sc, const float* __restrict__ bi,
    const float* __restrict__ mu, const float* __restrict__ var,
    const float* __restrict__ x, u16* __restrict__ zt) {
  __shared__ float Ls[4][64];          // 1/l per (group, row-in-block)
  const int b = blockIdx.z, oc = blockIdx.y, nb = blockIdx.x * 64;
  const int tid = threadIdx.x;
  {
    int g = tid >> 6, row = tid & 63;
    float l = 0.f;
#pragma unroll
    for (int ks = 0; ks < 7; ++ks)
      l += LP[(size_t)(ks * 16 + b * 4 + g) * NPIX + nb + row];
    Ls[g][row] = 1.0f / l;
  }
  __syncthreads();
  const int wv = tid >> 6, lane = tid & 63;
  const int lr = lane & 15, lq = lane >> 4;
  const int nrow = nb + wv * 16;
  f32x4 acc[4][4] = {};                // [g][ot]
#pragma unroll
  for (int g = 0; g < 4; ++g) {
    bf16x8 bf[4];
#pragma unroll
    for (int ot = 0; ot < 4; ++ot)
      bf[ot] = *(const bf16x8*)(Wwb + (size_t)(oc * 64 + ot * 16 + lr) * 128 + g * 32 + lq * 8);
#pragma unroll
    for (int ks = 0; ks < 7; ++ks) {
      bf16x8 af = *(const bf16x8*)(OPb +
          ((size_t)(ks * 16 + b * 4 + g) * NPIX + nrow + lr) * 32 + lq * 8);
#pragma unroll
      for (int ot = 0; ot < 4; ++ot)
        acc[g][ot] = mfma(af, bf[ot], acc[g][ot]);
    }
  }
#pragma unroll
  for (int ot = 0; ot < 4; ++ot) {
    const int o = oc * 64 + ot * 16 + lr;
    float inv = sc[o] * rsqrtf(var[o] + 1e-5f);
    float off = bi[o] - mu[o] * inv + Wb[o] * inv;
    const int qn = nrow + lq * 4;
    float4 xr = *(const float4*)(x + ((size_t)b * 256 + o) * NPIX + qn);
    float xv[4] = {xr.x, xr.y, xr.z, xr.w};
#pragma unroll
    for (int r = 0; r < 4; ++r) {
      int row = wv * 16 + lq * 4 + r;
      float y = acc[0][ot][r] * Ls[0][row] + acc[1][ot][r] * Ls[1][row] +
                acc[2][ot][r] * Ls[2][row] + acc[3][ot][r] * Ls[3][row];
      float v = fmaxf(y * inv + off + xv[r], 0.f);
      zt[((size_t)b * NPIX + qn + r) * 256 + o] = f2b(v);
    }
  }
}

// ---------------------------------------------------------------------------
// ff1: o1t(n,64) = relu(bn1(f1 . z)); 2-tile, o-split x2 (wave 32n x 32o)
// ---------------------------------------------------------------------------
__global__ __launch_bounds__(256) void ff1_kernel(
    const u16* __restrict__ zt, const u16* __restrict__ f1b,
    const float* __restrict__ sc, const float* __restrict__ bi,
    const float* __restrict__ mu, const float* __restrict__ var,
    u16* __restrict__ o1t) {
  const int b = blockIdx.z, oc = blockIdx.y, nb = blockIdx.x * 128;
  const int wv = threadIdx.x >> 6, lane = threadIdx.x & 63;
  const int lr = lane & 15, lq = lane >> 4;
  const int nrow0 = nb + wv * 32, nrow1 = nrow0 + 16;
  const int r0 = nrow0 + lr < NPIX ? nrow0 + lr : NPIX - 1;
  const int r1 = nrow1 + lr < NPIX ? nrow1 + lr : NPIX - 1;
  f32x4 acc[4] = {};
  mf_gemm2<8, 2>(zt + ((size_t)b * NPIX + r0) * 256,
                 zt + ((size_t)b * NPIX + r1) * 256,
                 f1b + (size_t)(oc * 32 + lr) * 256, 256, lq, acc);
#pragma unroll
  for (int t = 0; t < 2; ++t) {
    const int qn = (t ? nrow1 : nrow0) + lq * 4;
    if (qn >= NPIX) continue;
#pragma unroll
    for (int ot = 0; ot < 2; ++ot) {
      const f32x4 a = acc[t * 2 + ot];
      const int o = oc * 32 + ot * 16 + lr;
      float inv = sc[o] * rsqrtf(var[o] + 1e-5f);
      float off = bi[o] - mu[o] * inv;
#pragma unroll
      for (int r = 0; r < 4; ++r) {
        float v = fmaxf(a[r] * inv + off, 0.f);
        o1t[((size_t)b * NPIX + qn + r) * 64 + o] = f2b(v);
      }
    }
  }
}

// ---------------------------------------------------------------------------
// ff2: o2t(n,64) = relu(bn2(conv3x3(o1))) im2col MFMA; 2-tile, o-split x2.
// ---------------------------------------------------------------------------
__global__ __launch_bounds__(256) void ff2_kernel(
    const u16* __restrict__ o1t, const u16* __restrict__ f2p,
    const float* __restrict__ sc, const float* __restrict__ bi,
    const float* __restrict__ mu, const float* __restrict__ var,
    u16* __restrict__ o2t) {
  const int b = blockIdx.z, oc = blockIdx.y, nb = blockIdx.x * 128;
  const int wv = threadIdx.x >> 6, lane = threadIdx.x & 63;
  const int lr = lane & 15, lq = lane >> 4;
  const int n0 = nb + wv * 32 + lr, n1 = n0 + 16;
  const int h0 = n0 / 56, w0 = n0 % 56;
  const int h1 = n1 / 56, w1 = n1 % 56;
  f32x4 acc[4] = {};
#pragma unroll
  for (int t = 0; t < 9; ++t) {
    const int dh = t / 3 - 1, dw = t % 3 - 1;
    const bool v0 = (h0 + dh) >= 0 && (h0 + dh) < 56 && (w0 + dw) >= 0 && (w0 + dw) < 56;
    const bool v1 = (h1 + dh) >= 0 && (h1 + dh) < 56 && (w1 + dw) >= 0 && (w1 + dw) < 56;
    const u16* A0 = o1t + ((size_t)b * NPIX + n0 + dh * 56 + dw) * 64;
    const u16* A1 = o1t + ((size_t)b * NPIX + n1 + dh * 56 + dw) * 64;
    const u16* Br = f2p + (size_t)t * 4096 + (size_t)(oc * 32 + lr) * 64;
#pragma unroll
    for (int k2 = 0; k2 < 2; ++k2) {
      bf16x8 bf0 = *(const bf16x8*)(Br + k2 * 32 + lq * 8);
      bf16x8 bf1 = *(const bf16x8*)(Br + (size_t)16 * 64 + k2 * 32 + lq * 8);
      bf16x8 a0 = {}, a1 = {};
      if (v0) a0 = *(const bf16x8*)(A0 + k2 * 32 + lq * 8);
      if (v1) a1 = *(const bf16x8*)(A1 + k2 * 32 + lq * 8);
      acc[0] = mfma(a0, bf0, acc[0]);
      acc[1] = mfma(a0, bf1, acc[1]);
      acc[2] = mfma(a1, bf0, acc[2]);
      acc[3] = mfma(a1, bf1, acc[3]);
    }
  }
  const int nrow0 = nb + wv * 32;
#pragma unroll
  for (int t = 0; t < 2; ++t) {
    const int qn = nrow0 + t * 16 + lq * 4;
    if (qn >= NPIX) continue;
#pragma unroll
    for (int ot = 0; ot < 2; ++ot) {
      const f32x4 a = acc[t * 2 + ot];
      const int o = oc * 32 + ot * 16 + lr;
      float inv = sc[o] * rsqrtf(var[o] + 1e-5f);
      float off = bi[o] - mu[o] * inv;
#pragma unroll
      for (int r = 0; r < 4; ++r) {
        float v = fmaxf(a[r] * inv + off, 0.f);
        o2t[((size_t)b * NPIX + qn + r) * 64 + o] = f2b(v);
      }
    }
  }
}

// ---------------------------------------------------------------------------
// ff3: out(b,256,N) fp32 = relu(bn3(f3 . o2) + z); 2-tile.
// ---------------------------------------------------------------------------
__global__ __launch_bounds__(256) void ff3_kernel(
    const u16* __restrict__ o2t, const u16* __restrict__ f3b,
    const float* __restrict__ sc, const float* __restrict__ bi,
    const float* __restrict__ mu, const float* __restrict__ var,
    const u16* __restrict__ zt, float* __restrict__ out) {
  const int b = blockIdx.z, oc = blockIdx.y, nb = blockIdx.x * 128;
  const int wv = threadIdx.x >> 6, lane = threadIdx.x & 63;
  const int lr = lane & 15, lq = lane >> 4;
  const int nrow0 = nb + wv * 32, nrow1 = nrow0 + 16;
  const int r0 = nrow0 + lr < NPIX ? nrow0 + lr : NPIX - 1;
  const int r1 = nrow1 + lr < NPIX ? nrow1 + lr : NPIX - 1;
  f32x4 acc[8] = {};
  mf_gemm2<2, 4>(o2t + ((size_t)b * NPIX + r0) * 64,
                 o2t + ((size_t)b * NPIX + r1) * 64,
                 f3b + (size_t)(oc * 64 + lr) * 64, 64, lq, acc);
#pragma unroll
  for (int t = 0; t < 2; ++t) {
    const int qn = (t ? nrow1 : nrow0) + lq * 4;
    if (qn >= NPIX) continue;
#pragma unroll
    for (int ot = 0; ot < 4; ++ot) {
      const f32x4 a = acc[t * 4 + ot];
      const int o = oc * 64 + ot * 16 + lr;
      float inv = sc[o] * rsqrtf(var[o] + 1e-5f);
      float off = bi[o] - mu[o] * inv;
      float4 s;
      float* sv = (float*)&s;
#pragma unroll
      for (int r = 0; r < 4; ++r) {
        float zres = b2f(zt[((size_t)b * NPIX + qn + r) * 256 + o]);
        sv[r] = fmaxf(a[r] * inv + off + zres, 0.f);
      }
      *(float4*)(out + ((size_t)b * 256 + o) * NPIX + qn) = s;
    }
  }
}

// ---------------------------------------------------------------------------
extern "C" void kernel_launch(void* const* d_in, const int* in_sizes, int n_in,
                              void* d_out, int out_size, void* d_ws, size_t ws_size,
                              hipStream_t stream) {
  const float* x    = (const float*)d_in[0];
  const float* gw   = (const float*)d_in[1];
  const float* gb   = (const float*)d_in[2];
  const float* tw   = (const float*)d_in[3];
  const float* tb   = (const float*)d_in[4];
  const float* pw   = (const float*)d_in[5];
  const float* pb   = (const float*)d_in[6];
  const float* Ww   = (const float*)d_in[7];
  const float* Wb   = (const float*)d_in[8];
  const float* bnWs = (const float*)d_in[9];
  const float* bnWb = (const float*)d_in[10];
  const float* bnWm = (const float*)d_in[11];
  const float* bnWv = (const float*)d_in[12];
  const float* f1w  = (const float*)d_in[13];
  const float* b1s  = (const float*)d_in[14];
  const float* b1b  = (const float*)d_in[15];
  const float* b1m  = (const float*)d_in[16];
  const float* b1v  = (const float*)d_in[17];
  const float* f2w  = (const float*)d_in[18];
  const float* b2s  = (const float*)d_in[19];
  const float* b2b  = (const float*)d_in[20];
  const float* b2m  = (const float*)d_in[21];
  const float* b2v  = (const float*)d_in[22];
  const float* f3w  = (const float*)d_in[23];
  const float* b3s  = (const float*)d_in[24];
  const float* b3b  = (const float*)d_in[25];
  const float* b3m  = (const float*)d_in[26];
  const float* b3v  = (const float*)d_in[27];
  float* out = (float*)d_out;

  u16* p = (u16*)d_ws;
  u16* gwb = p; p += 128 * 256;
  u16* twb = p; p += 128 * 256;
  u16* pwb = p; p += 128 * 256;
  u16* Wwb = p; p += 256 * 128;
  u16* f1b = p; p += 64 * 256;
  u16* f3b = p; p += 256 * 64;
  u16* f2p = p; p += 9 * 64 * 64;
  u16* Tq  = p; p += (size_t)16 * NPIX * 32;
  u16* Pk  = p; p += (size_t)16 * NPIX * 32;
  u16* gx  = p; p += (size_t)BB * 128 * NPIX;
  u16* OPb = p; p += (size_t)7 * 16 * NPIX * 32;
  float* LP = (float*)p; p += (size_t)7 * 16 * NPIX * 2;
  u16* zt  = p; p += (size_t)BB * NPIX * 256;
  u16* o1t = p; p += (size_t)BB * NPIX * 64;
  u16* o2t = p; p += (size_t)BB * NPIX * 64;

  prep_w<<<dim3(196), 256, 0, stream>>>(gw, tw, pw, Ww, f1w, f2w, f3w,
                                        gwb, twb, pwb, Wwb, f1b, f3b, f2p);
  proj_kernel<<<dim3(49, BB), 256, 0, stream>>>(x, gwb, twb, pwb, gb, tb, pb,
                                                gx, Tq, Pk);
  attn_kernel<<<dim3(2800), 256, 0, stream>>>(Tq, Pk, gx, OPb, LP);
  wz_kernel<<<dim3(49, 4, BB), 256, 0, stream>>>(OPb, LP, Wwb, Wb,
                                                 bnWs, bnWb, bnWm, bnWv, x, zt);
  ff1_kernel<<<dim3(25, 2, BB), 256, 0, stream>>>(zt, f1b, b1s, b1b, b1m, b1v, o1t);
  ff2_kernel<<<dim3(25, 2, BB), 256, 0, stream>>>(o1t, f2p, b2s, b2b, b2m, b2v, o2t);
  ff3_kernel<<<dim3(25, 4, BB), 256, 0, stream>>>(o2t, f3b, b3s, b3b, b3m, b3v, zt, out);
}

// Round 12
// 248.938 us; speedup vs baseline: 1.1065x; 1.1065x over previous
//
#include <hip/hip_runtime.h>
#include <hip/hip_bf16.h>

#define NPIX 3136
#define BB 4
#define LOG2E 1.4426950408889634f

typedef unsigned short u16;
typedef __bf16 bf16x8 __attribute__((ext_vector_type(8)));
typedef float f32x4 __attribute__((ext_vector_type(4)));

__device__ __forceinline__ float b2f(u16 u) {
  union { unsigned u; float f; } c; c.u = ((unsigned)u) << 16; return c.f;
}
__device__ __forceinline__ u16 f2b(float f) {
  __hip_bfloat16 h = __float2bfloat16(f);
  return *reinterpret_cast<u16*>(&h);
}
__device__ __forceinline__ unsigned pk2(float a, float b) {
  return (unsigned)f2b(a) | ((unsigned)f2b(b) << 16);
}
__device__ __forceinline__ f32x4 mfma(bf16x8 a, bf16x8 b, f32x4 c) {
  return __builtin_amdgcn_mfma_f32_16x16x32_bf16(a, b, c, 0, 0, 0);
}

// ---------------------------------------------------------------------------
// 2-tile MFMA wave-GEMM (R10, used by proj/ff1/ff3).
// ---------------------------------------------------------------------------
template<int NSTEP, int NOT>
__device__ __forceinline__ void mf_gemm2(const u16* __restrict__ A0,
                                         const u16* __restrict__ A1,
                                         const u16* __restrict__ Brow, int sB,
                                         int lq, f32x4* acc) {
#pragma unroll
  for (int s = 0; s < NSTEP; ++s) {
    bf16x8 bf[NOT];
#pragma unroll
    for (int ot = 0; ot < NOT; ++ot)
      bf[ot] = *(const bf16x8*)(Brow + (size_t)ot * 16 * sB + s * 32 + lq * 8);
    bf16x8 a0 = *(const bf16x8*)(A0 + s * 32 + lq * 8);
    bf16x8 a1 = *(const bf16x8*)(A1 + s * 32 + lq * 8);
#pragma unroll
    for (int ot = 0; ot < NOT; ++ot) {
      acc[ot] = mfma(a0, bf[ot], acc[ot]);
      acc[NOT + ot] = mfma(a1, bf[ot], acc[NOT + ot]);
    }
  }
}

// ---------------------------------------------------------------------------
// prep_w: weights -> bf16. theta weights pre-scaled by log2(e).
// ---------------------------------------------------------------------------
__global__ __launch_bounds__(256) void prep_w(
    const float* __restrict__ gw, const float* __restrict__ tw,
    const float* __restrict__ pw, const float* __restrict__ Ww,
    const float* __restrict__ f1w, const float* __restrict__ f2w,
    const float* __restrict__ f3w,
    u16* __restrict__ gwb, u16* __restrict__ twb, u16* __restrict__ pwb,
    u16* __restrict__ Wwb, u16* __restrict__ f1b, u16* __restrict__ f3b,
    u16* __restrict__ f2p) {
  for (int i = blockIdx.x * 256 + threadIdx.x; i < 200704; i += gridDim.x * 256) {
    int j = i;
    if (j < 32768) { gwb[j] = f2b(gw[j]); continue; } j -= 32768;
    if (j < 32768) { twb[j] = f2b(tw[j] * LOG2E); continue; } j -= 32768;
    if (j < 32768) { pwb[j] = f2b(pw[j]); continue; } j -= 32768;
    if (j < 32768) { Wwb[j] = f2b(Ww[j]); continue; } j -= 32768;
    if (j < 16384) { f1b[j] = f2b(f1w[j]); continue; } j -= 16384;
    if (j < 16384) { f3b[j] = f2b(f3w[j]); continue; } j -= 16384;
    int t = j >> 12, rem = j & 4095, co = rem >> 6, ci = rem & 63;
    f2p[j] = f2b(f2w[(co * 64 + ci) * 9 + t]);
  }
}

// ---------------------------------------------------------------------------
// prep_x: xt[b][n][c] = bf16(x[b][c][n]) via 64x64 LDS tile transpose.
// ---------------------------------------------------------------------------
__global__ __launch_bounds__(256) void prep_x(const float* __restrict__ x,
                                              u16* __restrict__ xt) {
  __shared__ u16 sT[64 * 65];
  const int b = blockIdx.z, c0 = blockIdx.y * 64, n0 = blockIdx.x * 64;
  const int t = threadIdx.x;
#pragma unroll
  for (int cc = 0; cc < 4; ++cc) {
    int c = cc * 16 + (t >> 4), n4 = (t & 15) * 4;
    float4 v = *(const float4*)(x + ((size_t)(b * 256 + c0 + c)) * NPIX + n0 + n4);
    sT[c * 65 + n4 + 0] = f2b(v.x);
    sT[c * 65 + n4 + 1] = f2b(v.y);
    sT[c * 65 + n4 + 2] = f2b(v.z);
    sT[c * 65 + n4 + 3] = f2b(v.w);
  }
  __syncthreads();
#pragma unroll
  for (int nn = 0; nn < 4; ++nn) {
    int n = nn * 16 + (t >> 4), c4 = (t & 15) * 4;
    uint2 s;
    s.x = (unsigned)sT[(c4 + 0) * 65 + n] | ((unsigned)sT[(c4 + 1) * 65 + n] << 16);
    s.y = (unsigned)sT[(c4 + 2) * 65 + n] | ((unsigned)sT[(c4 + 3) * 65 + n] << 16);
    *(uint2*)(xt + ((size_t)b * NPIX + n0 + n) * 256 + c0 + c4) = s;
  }
}

// ---------------------------------------------------------------------------
// proj: R10 2-tile MFMA. oc section: 0,1=g 2,3=theta 4,5=phi. Grid (25,6,BB).
// ---------------------------------------------------------------------------
__global__ __launch_bounds__(256) void proj_kernel(
    const u16* __restrict__ xt,
    const u16* __restrict__ gwb, const u16* __restrict__ twb, const u16* __restrict__ pwb,
    const float* __restrict__ gb, const float* __restrict__ tb, const float* __restrict__ pb,
    u16* __restrict__ gx, u16* __restrict__ Tq, u16* __restrict__ Pk) {
  const int b = blockIdx.z, oc = blockIdx.y, nb = blockIdx.x * 128;
  const int sec = oc >> 1, rbase = (oc & 1) * 64;
  const u16* wsel = sec == 0 ? gwb : (sec == 1 ? twb : pwb);
  const float* bsel = sec == 0 ? gb : (sec == 1 ? tb : pb);
  const int wv = threadIdx.x >> 6, lane = threadIdx.x & 63;
  const int lr = lane & 15, lq = lane >> 4;
  const int nrow0 = nb + wv * 32, nrow1 = nrow0 + 16;
  const int r0 = nrow0 + lr < NPIX ? nrow0 + lr : NPIX - 1;
  const int r1 = nrow1 + lr < NPIX ? nrow1 + lr : NPIX - 1;
  f32x4 acc[8] = {};
  mf_gemm2<8, 4>(xt + ((size_t)b * NPIX + r0) * 256,
                 xt + ((size_t)b * NPIX + r1) * 256,
                 wsel + (size_t)(rbase + lr) * 256, 256, lq, acc);
#pragma unroll
  for (int t = 0; t < 2; ++t) {
    const int qn = (t ? nrow1 : nrow0) + lq * 4;
    if (qn >= NPIX) continue;
#pragma unroll
    for (int ot = 0; ot < 4; ++ot) {
      const f32x4 a = acc[t * 4 + ot];
      const int o = rbase + ot * 16 + lr;
      float bias = bsel[o];
      if (sec == 1) bias *= LOG2E;
      if (sec == 0) {
        uint2 s;
        s.x = pk2(a[0] + bias, a[1] + bias);
        s.y = pk2(a[2] + bias, a[3] + bias);
        *(uint2*)(gx + ((size_t)b * 128 + o) * NPIX + qn) = s;
      } else {
        const int g = o >> 5, dl = o & 31;
        u16* dst = sec == 1 ? Tq : Pk;
        size_t base = (size_t)(b * 4 + g) * NPIX;
#pragma unroll
        for (int r = 0; r < 4; ++r)
          dst[(base + qn + r) * 32 + dl] = f2b(a[r] + bias);
      }
    }
  }
}

// ---------------------------------------------------------------------------
// attn: UNCHANGED from R10 (74.4 us, no spills).
// ---------------------------------------------------------------------------
__global__ __launch_bounds__(256) void attn_kernel(
    const u16* __restrict__ Tq, const u16* __restrict__ Pk,
    const u16* __restrict__ gx, u16* __restrict__ OPb, float* __restrict__ LP) {
  __shared__ __align__(16) u16 Plds[4][32][40];
  const int bid = blockIdx.x;
  const int ks = bid / 400, rem = bid % 400;
  const int bg = rem / 25, qblk = rem % 25;
  const int b = bg >> 2, g = bg & 3;
  const int wave = threadIdx.x >> 6, lane = threadIdx.x & 63;
  const int lr = lane & 15, lq = lane >> 4;
  const int qbase = qblk * 128 + wave * 32;
  const int kc0 = ks * 448;
  const u16* Qp = Tq + (size_t)bg * NPIX * 32;
  const u16* Kp = Pk + (size_t)bg * NPIX * 32;
  const u16* Vp = gx + ((size_t)b * 128 + g * 32) * NPIX;

  bf16x8 qf[2];
#pragma unroll
  for (int qi = 0; qi < 2; ++qi) {
    int row = qbase + qi * 16 + lr;
    row = row < NPIX ? row : NPIX - 1;
    qf[qi] = *(const bf16x8*)(Qp + (size_t)row * 32 + lq * 8);
  }
  const f32x4 z4 = {0.f, 0.f, 0.f, 0.f};
  f32x4 O[2][2], Lf[2];
#pragma unroll
  for (int qi = 0; qi < 2; ++qi) { O[qi][0] = z4; O[qi][1] = z4; Lf[qi] = z4; }
  bf16x8 onef;
#pragma unroll
  for (int j = 0; j < 8; ++j) onef[j] = (__bf16)1.0f;

#pragma unroll 1
  for (int kc = kc0; kc < kc0 + 448; kc += 32) {
    bf16x8 kf0 = *(const bf16x8*)(Kp + (size_t)(kc + lr) * 32 + lq * 8);
    bf16x8 kf1 = *(const bf16x8*)(Kp + (size_t)(kc + 16 + lr) * 32 + lq * 8);
    f32x4 S[2][2];
    S[0][0] = mfma(qf[0], kf0, z4);
    S[0][1] = mfma(qf[0], kf1, z4);
    S[1][0] = mfma(qf[1], kf0, z4);
    S[1][1] = mfma(qf[1], kf1, z4);
#pragma unroll
    for (int qi = 0; qi < 2; ++qi)
#pragma unroll
      for (int kt = 0; kt < 2; ++kt)
#pragma unroll
        for (int r = 0; r < 4; ++r) {
          unsigned u = __builtin_bit_cast(unsigned, __builtin_exp2f(S[qi][kt][r]));
          Plds[wave][qi * 16 + lq * 4 + r][kt * 16 + lr] = (u16)(u >> 16);
        }
    bf16x8 pf0 = *(const bf16x8*)(&Plds[wave][lr][lq * 8]);
    bf16x8 pf1 = *(const bf16x8*)(&Plds[wave][16 + lr][lq * 8]);
    bf16x8 vf0 = *(const bf16x8*)(Vp + (size_t)lr * NPIX + kc + lq * 8);
    bf16x8 vf1 = *(const bf16x8*)(Vp + (size_t)(16 + lr) * NPIX + kc + lq * 8);
    O[0][0] = mfma(pf0, vf0, O[0][0]);
    O[0][1] = mfma(pf0, vf1, O[0][1]);
    O[1][0] = mfma(pf1, vf0, O[1][0]);
    O[1][1] = mfma(pf1, vf1, O[1][1]);
    Lf[0] = mfma(pf0, onef, Lf[0]);
    Lf[1] = mfma(pf1, onef, Lf[1]);
  }
  const size_t sbase = (size_t)(ks * 16 + bg) * NPIX;
#pragma unroll
  for (int qi = 0; qi < 2; ++qi) {
#pragma unroll
    for (int r = 0; r < 4; ++r) {
      int qrow = qbase + qi * 16 + lq * 4 + r;
      if (qrow < NPIX) {
        size_t ob = (sbase + qrow) * 32;
        OPb[ob + lr] = f2b(O[qi][0][r]);
        OPb[ob + 16 + lr] = f2b(O[qi][1][r]);
        if (lr == 0) LP[sbase + qrow] = Lf[qi][r];
      }
    }
  }
}

// ---------------------------------------------------------------------------
// wz-v2 (absorbs combine, traffic-correct): 512-thread blocks, grid (98,BB).
// Block owns 32 n-rows; 8 waves = 4 oc x 2 n-tiles, so the 4 oc waves share
// the same OPb rows via L1 -> OPb read ~once (22.5 MB, same as old combine).
// Per-g accumulators; per-(g,row) 1/l applied in epilogue (softmax norm is
// per-group, cannot commute past the channel sum).
// ---------------------------------------------------------------------------
__global__ __launch_bounds__(512) void wz_kernel(
    const u16* __restrict__ OPb, const float* __restrict__ LP,
    const u16* __restrict__ Wwb, const float* __restrict__ Wb,
    const float* __restrict__ sc, const float* __restrict__ bi,
    const float* __restrict__ mu, const float* __restrict__ var,
    const float* __restrict__ x, u16* __restrict__ zt) {
  __shared__ float Ls[4][32];
  const int b = blockIdx.y, nb = blockIdx.x * 32;
  const int tid = threadIdx.x;
  if (tid < 128) {
    int g = tid >> 5, row = tid & 31;
    float l = 0.f;
#pragma unroll
    for (int ks = 0; ks < 7; ++ks)
      l += LP[(size_t)(ks * 16 + b * 4 + g) * NPIX + nb + row];
    Ls[g][row] = 1.0f / l;
  }
  __syncthreads();
  const int wave = tid >> 6, lane = tid & 63;
  const int lr = lane & 15, lq = lane >> 4;
  const int oc = wave & 3, tt = wave >> 2;
  const int nrow = nb + tt * 16;
  f32x4 acc[4][4] = {};                // [g][ot]
#pragma unroll
  for (int g = 0; g < 4; ++g) {
    bf16x8 bf[4];
#pragma unroll
    for (int ot = 0; ot < 4; ++ot)
      bf[ot] = *(const bf16x8*)(Wwb + (size_t)(oc * 64 + ot * 16 + lr) * 128 + g * 32 + lq * 8);
#pragma unroll
    for (int ks = 0; ks < 7; ++ks) {
      bf16x8 af = *(const bf16x8*)(OPb +
          ((size_t)(ks * 16 + b * 4 + g) * NPIX + nrow + lr) * 32 + lq * 8);
#pragma unroll
      for (int ot = 0; ot < 4; ++ot)
        acc[g][ot] = mfma(af, bf[ot], acc[g][ot]);
    }
  }
#pragma unroll
  for (int ot = 0; ot < 4; ++ot) {
    const int o = oc * 64 + ot * 16 + lr;
    float inv = sc[o] * rsqrtf(var[o] + 1e-5f);
    float off = bi[o] - mu[o] * inv + Wb[o] * inv;
    const int qn = nrow + lq * 4;
    float4 xr = *(const float4*)(x + ((size_t)b * 256 + o) * NPIX + qn);
    float xv[4] = {xr.x, xr.y, xr.z, xr.w};
#pragma unroll
    for (int r = 0; r < 4; ++r) {
      int row = tt * 16 + lq * 4 + r;
      float y = acc[0][ot][r] * Ls[0][row] + acc[1][ot][r] * Ls[1][row] +
                acc[2][ot][r] * Ls[2][row] + acc[3][ot][r] * Ls[3][row];
      float v = fmaxf(y * inv + off + xv[r], 0.f);
      zt[((size_t)b * NPIX + qn + r) * 256 + o] = f2b(v);
    }
  }
}

// ---------------------------------------------------------------------------
// ff1: R10. o1t(n,64) = relu(bn1(f1 . z)); 2-tile, o-split x2.
// ---------------------------------------------------------------------------
__global__ __launch_bounds__(256) void ff1_kernel(
    const u16* __restrict__ zt, const u16* __restrict__ f1b,
    const float* __restrict__ sc, const float* __restrict__ bi,
    const float* __restrict__ mu, const float* __restrict__ var,
    u16* __restrict__ o1t) {
  const int b = blockIdx.z, oc = blockIdx.y, nb = blockIdx.x * 128;
  const int wv = threadIdx.x >> 6, lane = threadIdx.x & 63;
  const int lr = lane & 15, lq = lane >> 4;
  const int nrow0 = nb + wv * 32, nrow1 = nrow0 + 16;
  const int r0 = nrow0 + lr < NPIX ? nrow0 + lr : NPIX - 1;
  const int r1 = nrow1 + lr < NPIX ? nrow1 + lr : NPIX - 1;
  f32x4 acc[4] = {};
  mf_gemm2<8, 2>(zt + ((size_t)b * NPIX + r0) * 256,
                 zt + ((size_t)b * NPIX + r1) * 256,
                 f1b + (size_t)(oc * 32 + lr) * 256, 256, lq, acc);
#pragma unroll
  for (int t = 0; t < 2; ++t) {
    const int qn = (t ? nrow1 : nrow0) + lq * 4;
    if (qn >= NPIX) continue;
#pragma unroll
    for (int ot = 0; ot < 2; ++ot) {
      const f32x4 a = acc[t * 2 + ot];
      const int o = oc * 32 + ot * 16 + lr;
      float inv = sc[o] * rsqrtf(var[o] + 1e-5f);
      float off = bi[o] - mu[o] * inv;
#pragma unroll
      for (int r = 0; r < 4; ++r) {
        float v = fmaxf(a[r] * inv + off, 0.f);
        o1t[((size_t)b * NPIX + qn + r) * 64 + o] = f2b(v);
      }
    }
  }
}

// ---------------------------------------------------------------------------
// ff2: R10. o2t(n,64) = relu(bn2(conv3x3(o1))) im2col MFMA; 2-tile.
// ---------------------------------------------------------------------------
__global__ __launch_bounds__(256) void ff2_kernel(
    const u16* __restrict__ o1t, const u16* __restrict__ f2p,
    const float* __restrict__ sc, const float* __restrict__ bi,
    const float* __restrict__ mu, const float* __restrict__ var,
    u16* __restrict__ o2t) {
  const int b = blockIdx.z, oc = blockIdx.y, nb = blockIdx.x * 128;
  const int wv = threadIdx.x >> 6, lane = threadIdx.x & 63;
  const int lr = lane & 15, lq = lane >> 4;
  const int n0 = nb + wv * 32 + lr, n1 = n0 + 16;
  const int h0 = n0 / 56, w0 = n0 % 56;
  const int h1 = n1 / 56, w1 = n1 % 56;
  f32x4 acc[4] = {};
#pragma unroll
  for (int t = 0; t < 9; ++t) {
    const int dh = t / 3 - 1, dw = t % 3 - 1;
    const bool v0 = (h0 + dh) >= 0 && (h0 + dh) < 56 && (w0 + dw) >= 0 && (w0 + dw) < 56;
    const bool v1 = (h1 + dh) >= 0 && (h1 + dh) < 56 && (w1 + dw) >= 0 && (w1 + dw) < 56;
    const u16* A0 = o1t + ((size_t)b * NPIX + n0 + dh * 56 + dw) * 64;
    const u16* A1 = o1t + ((size_t)b * NPIX + n1 + dh * 56 + dw) * 64;
    const u16* Br = f2p + (size_t)t * 4096 + (size_t)(oc * 32 + lr) * 64;
#pragma unroll
    for (int k2 = 0; k2 < 2; ++k2) {
      bf16x8 bf0 = *(const bf16x8*)(Br + k2 * 32 + lq * 8);
      bf16x8 bf1 = *(const bf16x8*)(Br + (size_t)16 * 64 + k2 * 32 + lq * 8);
      bf16x8 a0 = {}, a1 = {};
      if (v0) a0 = *(const bf16x8*)(A0 + k2 * 32 + lq * 8);
      if (v1) a1 = *(const bf16x8*)(A1 + k2 * 32 + lq * 8);
      acc[0] = mfma(a0, bf0, acc[0]);
      acc[1] = mfma(a0, bf1, acc[1]);
      acc[2] = mfma(a1, bf0, acc[2]);
      acc[3] = mfma(a1, bf1, acc[3]);
    }
  }
  const int nrow0 = nb + wv * 32;
#pragma unroll
  for (int t = 0; t < 2; ++t) {
    const int qn = nrow0 + t * 16 + lq * 4;
    if (qn >= NPIX) continue;
#pragma unroll
    for (int ot = 0; ot < 2; ++ot) {
      const f32x4 a = acc[t * 2 + ot];
      const int o = oc * 32 + ot * 16 + lr;
      float inv = sc[o] * rsqrtf(var[o] + 1e-5f);
      float off = bi[o] - mu[o] * inv;
#pragma unroll
      for (int r = 0; r < 4; ++r) {
        float v = fmaxf(a[r] * inv + off, 0.f);
        o2t[((size_t)b * NPIX + qn + r) * 64 + o] = f2b(v);
      }
    }
  }
}

// ---------------------------------------------------------------------------
// ff3: R10. out(b,256,N) fp32 = relu(bn3(f3 . o2) + z); 2-tile.
// ---------------------------------------------------------------------------
__global__ __launch_bounds__(256) void ff3_kernel(
    const u16* __restrict__ o2t, const u16* __restrict__ f3b,
    const float* __restrict__ sc, const float* __restrict__ bi,
    const float* __restrict__ mu, const float* __restrict__ var,
    const u16* __restrict__ zt, float* __restrict__ out) {
  const int b = blockIdx.z, oc = blockIdx.y, nb = blockIdx.x * 128;
  const int wv = threadIdx.x >> 6, lane = threadIdx.x & 63;
  const int lr = lane & 15, lq = lane >> 4;
  const int nrow0 = nb + wv * 32, nrow1 = nrow0 + 16;
  const int r0 = nrow0 + lr < NPIX ? nrow0 + lr : NPIX - 1;
  const int r1 = nrow1 + lr < NPIX ? nrow1 + lr : NPIX - 1;
  f32x4 acc[8] = {};
  mf_gemm2<2, 4>(o2t + ((size_t)b * NPIX + r0) * 64,
                 o2t + ((size_t)b * NPIX + r1) * 64,
                 f3b + (size_t)(oc * 64 + lr) * 64, 64, lq, acc);
#pragma unroll
  for (int t = 0; t < 2; ++t) {
    const int qn = (t ? nrow1 : nrow0) + lq * 4;
    if (qn >= NPIX) continue;
#pragma unroll
    for (int ot = 0; ot < 4; ++ot) {
      const f32x4 a = acc[t * 4 + ot];
      const int o = oc * 64 + ot * 16 + lr;
      float inv = sc[o] * rsqrtf(var[o] + 1e-5f);
      float off = bi[o] - mu[o] * inv;
      float4 s;
      float* sv = (float*)&s;
#pragma unroll
      for (int r = 0; r < 4; ++r) {
        float zres = b2f(zt[((size_t)b * NPIX + qn + r) * 256 + o]);
        sv[r] = fmaxf(a[r] * inv + off + zres, 0.f);
      }
      *(float4*)(out + ((size_t)b * 256 + o) * NPIX + qn) = s;
    }
  }
}

// ---------------------------------------------------------------------------
extern "C" void kernel_launch(void* const* d_in, const int* in_sizes, int n_in,
                              void* d_out, int out_size, void* d_ws, size_t ws_size,
                              hipStream_t stream) {
  const float* x    = (const float*)d_in[0];
  const float* gw   = (const float*)d_in[1];
  const float* gb   = (const float*)d_in[2];
  const float* tw   = (const float*)d_in[3];
  const float* tb   = (const float*)d_in[4];
  const float* pw   = (const float*)d_in[5];
  const float* pb   = (const float*)d_in[6];
  const float* Ww   = (const float*)d_in[7];
  const float* Wb   = (const float*)d_in[8];
  const float* bnWs = (const float*)d_in[9];
  const float* bnWb = (const float*)d_in[10];
  const float* bnWm = (const float*)d_in[11];
  const float* bnWv = (const float*)d_in[12];
  const float* f1w  = (const float*)d_in[13];
  const float* b1s  = (const float*)d_in[14];
  const float* b1b  = (const float*)d_in[15];
  const float* b1m  = (const float*)d_in[16];
  const float* b1v  = (const float*)d_in[17];
  const float* f2w  = (const float*)d_in[18];
  const float* b2s  = (const float*)d_in[19];
  const float* b2b  = (const float*)d_in[20];
  const float* b2m  = (const float*)d_in[21];
  const float* b2v  = (const float*)d_in[22];
  const float* f3w  = (const float*)d_in[23];
  const float* b3s  = (const float*)d_in[24];
  const float* b3b  = (const float*)d_in[25];
  const float* b3m  = (const float*)d_in[26];
  const float* b3v  = (const float*)d_in[27];
  float* out = (float*)d_out;

  u16* p = (u16*)d_ws;
  u16* xt  = p; p += (size_t)BB * NPIX * 256;
  u16* gwb = p; p += 128 * 256;
  u16* twb = p; p += 128 * 256;
  u16* pwb = p; p += 128 * 256;
  u16* Wwb = p; p += 256 * 128;
  u16* f1b = p; p += 64 * 256;
  u16* f3b = p; p += 256 * 64;
  u16* f2p = p; p += 9 * 64 * 64;
  u16* Tq  = p; p += (size_t)16 * NPIX * 32;
  u16* Pk  = p; p += (size_t)16 * NPIX * 32;
  u16* gx  = p; p += (size_t)BB * 128 * NPIX;
  u16* OPb = p; p += (size_t)7 * 16 * NPIX * 32;
  float* LP = (float*)p; p += (size_t)7 * 16 * NPIX * 2;
  u16* zt  = p; p += (size_t)BB * NPIX * 256;
  u16* o1t = p; p += (size_t)BB * NPIX * 64;
  u16* o2t = p; p += (size_t)BB * NPIX * 64;

  prep_w<<<dim3(196), 256, 0, stream>>>(gw, tw, pw, Ww, f1w, f2w, f3w,
                                        gwb, twb, pwb, Wwb, f1b, f3b, f2p);
  prep_x<<<dim3(49, 4, BB), 256, 0, stream>>>(x, xt);
  proj_kernel<<<dim3(25, 6, BB), 256, 0, stream>>>(xt, gwb, twb, pwb, gb, tb, pb,
                                                   gx, Tq, Pk);
  attn_kernel<<<dim3(2800), 256, 0, stream>>>(Tq, Pk, gx, OPb, LP);
  wz_kernel<<<dim3(98, BB), 512, 0, stream>>>(OPb, LP, Wwb, Wb,
                                              bnWs, bnWb, bnWm, bnWv, x, zt);
  ff1_kernel<<<dim3(25, 2, BB), 256, 0, stream>>>(zt, f1b, b1s, b1b, b1m, b1v, o1t);
  ff2_kernel<<<dim3(25, 2, BB), 256, 0, stream>>>(o1t, f2p, b2s, b2b, b2m, b2v, o2t);
  ff3_kernel<<<dim3(25, 4, BB), 256, 0, stream>>>(o2t, f3b, b3s, b3b, b3m, b3v, zt, out);
}